// Round 1
// baseline (522.101 us; speedup 1.0000x reference)
//
#include <hip/hip_runtime.h>
#include <stdint.h>

#define DIM 128

typedef __attribute__((ext_vector_type(8))) short short8;
typedef __attribute__((ext_vector_type(4))) float f32x4;

static __device__ __forceinline__ uint16_t f2bf(float f) {
  uint32_t u = __builtin_bit_cast(uint32_t, f);
  uint32_t r = (u + 0x7fffu + ((u >> 16) & 1u)) >> 16;  // RNE
  return (uint16_t)r;
}
static __device__ __forceinline__ uint32_t pack2(float a, float b) {
  return (uint32_t)f2bf(a) | ((uint32_t)f2bf(b) << 16);
}

// ---------------- Phase 1: edge scatter-add (atomics) ----------------
// One edge per wave; lane l handles float2 at column 2l. Coalesced 512B row
// read; 128 fp32 atomics per edge into agg (= d_out).
__global__ __launch_bounds__(256) void scatter_kernel(
    const float* __restrict__ x, const int* __restrict__ src_idx,
    const int* __restrict__ dst_idx, float* __restrict__ agg, int n_edge)
{
  const int lane = threadIdx.x & 63;
  const int wv = (blockIdx.x * 256 + threadIdx.x) >> 6;
  const int nw = (gridDim.x * 256) >> 6;
  for (int e = wv; e < n_edge; e += nw) {
    const int s = src_idx[e];   // wave-uniform -> scalar load
    const int d = dst_idx[e];
    const float2 v = *reinterpret_cast<const float2*>(x + (size_t)s * DIM + lane * 2);
    float* o = agg + (size_t)d * DIM + lane * 2;
    atomicAdd(o, v.x);
    atomicAdd(o + 1, v.y);
  }
}

// ---------------- Phase 2: fused finish GEMM (in place) ----------------
// out[r][c] = sum_{k<128} (agg[r][k]/deg[r]) * W1[c][k]
//           + sum_{k<128} x[self[r]][k]      * W2[c][k]
// K=256 concat GEMM in bf16 MFMA 16x16x32. Block = 64 rows x 128 cols, 4 waves
// (wave w owns rows w*16..w*16+15, all 8 col-frags).
// LDS: Bs = 8 kst x 8 ct x 64 lanes x 8 bf16 (frag-order, 64KB, built once)
//      As = 64 rows x 264 bf16 (256 K + 8 pad -> stride 132 dwords, 2-way banks)
__global__ __launch_bounds__(256) void finish_kernel(
    float* __restrict__ io, const float* __restrict__ x,
    const float* __restrict__ W1, const float* __restrict__ W2,
    const float* __restrict__ degree, const int* __restrict__ self_ids,
    int n_dst)
{
  extern __shared__ char smem[];
  uint16_t* Bs = (uint16_t*)smem;              // 32768 bf16
  uint16_t* As = (uint16_t*)(smem + 65536);    // 64*264 bf16
  const int tid = threadIdx.x;
  const int r0 = blockIdx.x * 64;

  // Build B in fragment order: frag(kst,ct), lane ln holds
  // B[k = kst*32 + (ln>>4)*8 + j][c = ct*16 + (ln&15)], j=0..7.
  // B[k][c] = (k<128) ? W1[c][k] : W2[c][k-128]. One u32 = bf16 pair (j, j+1).
  uint32_t* Bs32 = (uint32_t*)Bs;
  for (int i = tid; i < 16384; i += 256) {
    const int e = i << 1;
    const int kst = e >> 12;
    const int ct  = (e >> 9) & 7;
    const int ln  = (e >> 3) & 63;
    const int j   = e & 7;
    const int k   = kst * 32 + ((ln >> 4) << 3) + j;
    const int c   = ct * 16 + (ln & 15);
    const float* w = (k < 128) ? (W1 + c * 128 + k) : (W2 + c * 128 + (k - 128));
    Bs32[i] = pack2(w[0], w[1]);
  }

  // Stage A tile: [scaled agg row | self row] -> bf16, row stride 264.
  for (int i = tid; i < 2048; i += 256) {       // 64 rows * 32 float4-groups
    const int r = i >> 5, g = i & 31;
    const int row = r0 + r;
    float4 va = {0.f, 0.f, 0.f, 0.f}, vs = {0.f, 0.f, 0.f, 0.f};
    float inv = 0.f;
    if (row < n_dst) {
      va = *reinterpret_cast<const float4*>(io + (size_t)row * DIM + g * 4);
      inv = 1.0f / degree[row];
      const int sid = self_ids[row];
      vs = *reinterpret_cast<const float4*>(x + (size_t)sid * DIM + g * 4);
    }
    uint32_t* pa = (uint32_t*)(As + r * 264 + g * 4);
    pa[0] = pack2(va.x * inv, va.y * inv);
    pa[1] = pack2(va.z * inv, va.w * inv);
    uint32_t* ps = (uint32_t*)(As + r * 264 + 128 + g * 4);
    ps[0] = pack2(vs.x, vs.y);
    ps[1] = pack2(vs.z, vs.w);
  }
  __syncthreads();

  const int wv = tid >> 6, lane = tid & 63;
  const uint16_t* Arow = As + (wv * 16 + (lane & 15)) * 264 + ((lane >> 4) << 3);
  const uint16_t* Bl = Bs + lane * 8;
  f32x4 acc[8] = {};
#pragma unroll
  for (int kst = 0; kst < 8; ++kst) {
    short8 a = *reinterpret_cast<const short8*>(Arow + kst * 32);
#pragma unroll
    for (int ct = 0; ct < 8; ++ct) {
      short8 b = *reinterpret_cast<const short8*>(Bl + (kst * 8 + ct) * 512);
      acc[ct] = __builtin_amdgcn_mfma_f32_16x16x32_bf16(a, b, acc[ct], 0, 0, 0);
    }
  }

  // C/D layout (m89-verified): col = lane&15, row = (lane>>4)*4 + reg.
  const int rbase = r0 + wv * 16 + ((lane >> 4) << 2);
  const int ccol = lane & 15;
#pragma unroll
  for (int ct = 0; ct < 8; ++ct) {
#pragma unroll
    for (int j = 0; j < 4; ++j) {
      const int row = rbase + j;
      if (row < n_dst) io[(size_t)row * DIM + ct * 16 + ccol] = acc[ct][j];
    }
  }
}

extern "C" void kernel_launch(void* const* d_in, const int* in_sizes, int n_in,
                              void* d_out, int out_size, void* d_ws, size_t ws_size,
                              hipStream_t stream) {
  const float* x        = (const float*)d_in[0];
  const float* W1       = (const float*)d_in[1];
  const float* W2       = (const float*)d_in[2];
  const float* degree   = (const float*)d_in[3];
  const int*   src_idx  = (const int*)d_in[4];
  const int*   dst_idx  = (const int*)d_in[5];
  const int*   self_ids = (const int*)d_in[6];
  float* out = (float*)d_out;
  const int n_dst  = in_sizes[3];
  const int n_edge = in_sizes[4];

  // agg accumulates directly in d_out; zero it every call (d_out not re-poisoned
  // between replays, so this keeps the launch deterministic).
  hipMemsetAsync(d_out, 0, (size_t)out_size * sizeof(float), stream);

  scatter_kernel<<<2048, 256, 0, stream>>>(x, src_idx, dst_idx, out, n_edge);

  const size_t lds_bytes = 65536 + 64 * 264 * 2;  // 99328
  hipFuncSetAttribute(reinterpret_cast<const void*>(finish_kernel),
                      hipFuncAttributeMaxDynamicSharedMemorySize, (int)lds_bytes);
  const int nblk = (n_dst + 63) / 64;
  finish_kernel<<<nblk, 256, lds_bytes, stream>>>(out, x, W1, W2, degree,
                                                  self_ids, n_dst);
}

// Round 2
// 210.446 us; speedup vs baseline: 2.4809x; 2.4809x over previous
//
#include <hip/hip_runtime.h>
#include <stdint.h>

#define DIM 128

typedef __attribute__((ext_vector_type(8))) short short8;
typedef __attribute__((ext_vector_type(4))) float f32x4;

static __device__ __forceinline__ uint16_t f2bf(float f) {
  uint32_t u = __builtin_bit_cast(uint32_t, f);
  uint32_t r = (u + 0x7fffu + ((u >> 16) & 1u)) >> 16;  // RNE
  return (uint16_t)r;
}
static __device__ __forceinline__ uint32_t pack2(float a, float b) {
  return (uint32_t)f2bf(a) | ((uint32_t)f2bf(b) << 16);
}

// ---------------- CSR build ----------------
__global__ __launch_bounds__(256) void hist_kernel(
    const int* __restrict__ dst, int* __restrict__ counts, int n_edge) {
  const int e = blockIdx.x * 256 + threadIdx.x;
  if (e < n_edge) atomicAdd(&counts[dst[e]], 1);
}

// Block-level inclusive scan (1024/block); row_ptr[i+1] = partial scan, bsum[b] = block total.
__global__ __launch_bounds__(1024) void scan1_kernel(
    const int* __restrict__ counts, int* __restrict__ row_ptr,
    int* __restrict__ bsum, int n) {
  __shared__ int sm[1024];
  const int t = threadIdx.x, i = blockIdx.x * 1024 + t;
  int v = (i < n) ? counts[i] : 0;
  sm[t] = v;
  __syncthreads();
  for (int off = 1; off < 1024; off <<= 1) {
    int a = (t >= off) ? sm[t - off] : 0;
    __syncthreads();
    sm[t] += a;
    __syncthreads();
  }
  if (i < n) row_ptr[i + 1] = sm[t];
  if (t == 1023) bsum[blockIdx.x] = sm[t];
}

// Single-block exclusive scan of block sums (nb <= 1024).
__global__ __launch_bounds__(1024) void scan2_kernel(int* __restrict__ bsum, int nb) {
  __shared__ int sm[1024];
  const int t = threadIdx.x;
  int v = (t < nb) ? bsum[t] : 0;
  sm[t] = v;
  __syncthreads();
  for (int off = 1; off < 1024; off <<= 1) {
    int a = (t >= off) ? sm[t - off] : 0;
    __syncthreads();
    sm[t] += a;
    __syncthreads();
  }
  if (t < nb) bsum[t] = sm[t] - v;  // exclusive
}

// Apply block offsets; also materialize cursor[] = segment starts.
__global__ __launch_bounds__(256) void scan3_kernel(
    int* __restrict__ row_ptr, int* __restrict__ cursor,
    const int* __restrict__ bsum, int n) {
  const int i = blockIdx.x * 256 + threadIdx.x;
  if (i < n) {
    const int v = row_ptr[i + 1] + bsum[i >> 10];
    row_ptr[i + 1] = v;
    if (i + 1 < n) cursor[i + 1] = v;
    if (i == 0) { row_ptr[0] = 0; cursor[0] = 0; }
  }
}

__global__ __launch_bounds__(256) void fill_kernel(
    const int* __restrict__ src, const int* __restrict__ dst,
    int* __restrict__ cursor, int* __restrict__ sorted, int n_edge) {
  const int e = blockIdx.x * 256 + threadIdx.x;
  if (e < n_edge) {
    const int pos = atomicAdd(&cursor[dst[e]], 1);
    sorted[pos] = src[e];
  }
}

// ---------------- Pull-mode aggregation ----------------
// One wave per dst node; lane l owns float2 at column 2l. Src ids are loaded
// 64-at-a-time by the wave and broadcast with __shfl so the x-row gathers
// issue back-to-back (no dependent index fetch per edge).
__global__ __launch_bounds__(256) void aggregate_kernel(
    const float* __restrict__ x, const int* __restrict__ row_ptr,
    const int* __restrict__ sorted, float* __restrict__ out, int n_dst) {
  const int lane = threadIdx.x & 63;
  const int d = (blockIdx.x * 256 + threadIdx.x) >> 6;
  if (d >= n_dst) return;
  const int beg = row_ptr[d], end = row_ptr[d + 1];
  float2 acc = {0.f, 0.f};
  for (int base = beg; base < end; base += 64) {
    const int m = end - base;
    const int myid = (lane < m) ? sorted[base + lane] : 0;
    const int cnt = m < 64 ? m : 64;
    for (int j = 0; j < cnt; ++j) {
      const int s = __shfl(myid, j);
      const float2 v = *reinterpret_cast<const float2*>(x + (size_t)s * DIM + lane * 2);
      acc.x += v.x;
      acc.y += v.y;
    }
  }
  *reinterpret_cast<float2*>(out + (size_t)d * DIM + lane * 2) = acc;
}

// ---------------- Fused finish GEMM (in place) ----------------
// out[r][c] = sum_{k<128} (agg[r][k]/deg[r]) * W1[c][k]
//           + sum_{k<128} x[self[r]][k]      * W2[c][k]
// K=256 concat GEMM in bf16 MFMA 16x16x32. Block = 64 rows x 128 cols, 4 waves.
__global__ __launch_bounds__(256) void finish_kernel(
    float* __restrict__ io, const float* __restrict__ x,
    const float* __restrict__ W1, const float* __restrict__ W2,
    const float* __restrict__ degree, const int* __restrict__ self_ids,
    int n_dst)
{
  extern __shared__ char smem[];
  uint16_t* Bs = (uint16_t*)smem;              // 32768 bf16, frag-order
  uint16_t* As = (uint16_t*)(smem + 65536);    // 64 rows x 264 bf16
  const int tid = threadIdx.x;
  const int r0 = blockIdx.x * 64;

  // B frag(kst,ct): lane ln holds B[k=kst*32+(ln>>4)*8+j][c=ct*16+(ln&15)], j=0..7.
  uint32_t* Bs32 = (uint32_t*)Bs;
  for (int i = tid; i < 16384; i += 256) {
    const int e = i << 1;
    const int kst = e >> 12;
    const int ct  = (e >> 9) & 7;
    const int ln  = (e >> 3) & 63;
    const int j   = e & 7;
    const int k   = kst * 32 + ((ln >> 4) << 3) + j;
    const int c   = ct * 16 + (ln & 15);
    const float* w = (k < 128) ? (W1 + c * 128 + k) : (W2 + c * 128 + (k - 128));
    Bs32[i] = pack2(w[0], w[1]);
  }

  // A tile: [agg/deg | x_self] -> bf16, row stride 264 (2-way banks only).
  for (int i = tid; i < 2048; i += 256) {
    const int r = i >> 5, g = i & 31;
    const int row = r0 + r;
    float4 va = {0.f, 0.f, 0.f, 0.f}, vs = {0.f, 0.f, 0.f, 0.f};
    float inv = 0.f;
    if (row < n_dst) {
      va = *reinterpret_cast<const float4*>(io + (size_t)row * DIM + g * 4);
      inv = 1.0f / degree[row];
      const int sid = self_ids[row];
      vs = *reinterpret_cast<const float4*>(x + (size_t)sid * DIM + g * 4);
    }
    uint32_t* pa = (uint32_t*)(As + r * 264 + g * 4);
    pa[0] = pack2(va.x * inv, va.y * inv);
    pa[1] = pack2(va.z * inv, va.w * inv);
    uint32_t* ps = (uint32_t*)(As + r * 264 + 128 + g * 4);
    ps[0] = pack2(vs.x, vs.y);
    ps[1] = pack2(vs.z, vs.w);
  }
  __syncthreads();

  const int wv = tid >> 6, lane = tid & 63;
  const uint16_t* Arow = As + (wv * 16 + (lane & 15)) * 264 + ((lane >> 4) << 3);
  const uint16_t* Bl = Bs + lane * 8;
  f32x4 acc[8] = {};
#pragma unroll
  for (int kst = 0; kst < 8; ++kst) {
    short8 a = *reinterpret_cast<const short8*>(Arow + kst * 32);
#pragma unroll
    for (int ct = 0; ct < 8; ++ct) {
      short8 b = *reinterpret_cast<const short8*>(Bl + (kst * 8 + ct) * 512);
      acc[ct] = __builtin_amdgcn_mfma_f32_16x16x32_bf16(a, b, acc[ct], 0, 0, 0);
    }
  }

  // C/D layout (m89): col = lane&15, row = (lane>>4)*4 + reg.
  const int rbase = r0 + wv * 16 + ((lane >> 4) << 2);
  const int ccol = lane & 15;
#pragma unroll
  for (int ct = 0; ct < 8; ++ct) {
#pragma unroll
    for (int j = 0; j < 4; ++j) {
      const int row = rbase + j;
      if (row < n_dst) io[(size_t)row * DIM + ct * 16 + ccol] = acc[ct][j];
    }
  }
}

extern "C" void kernel_launch(void* const* d_in, const int* in_sizes, int n_in,
                              void* d_out, int out_size, void* d_ws, size_t ws_size,
                              hipStream_t stream) {
  const float* x        = (const float*)d_in[0];
  const float* W1       = (const float*)d_in[1];
  const float* W2       = (const float*)d_in[2];
  const float* degree   = (const float*)d_in[3];
  const int*   src_idx  = (const int*)d_in[4];
  const int*   dst_idx  = (const int*)d_in[5];
  const int*   self_ids = (const int*)d_in[6];
  float* out = (float*)d_out;
  const int n_dst  = in_sizes[3];
  const int n_edge = in_sizes[4];

  // ws layout (256B aligned): counts | row_ptr | cursor | bsum | sorted_src
  auto align256 = [](size_t v) { return (v + 255) & ~(size_t)255; };
  char* ws = (char*)d_ws;
  size_t o_counts = 0;
  size_t o_rowptr = align256(o_counts + (size_t)n_dst * 4);
  size_t o_cursor = align256(o_rowptr + (size_t)(n_dst + 1) * 4);
  size_t o_bsum   = align256(o_cursor + (size_t)n_dst * 4);
  size_t o_sorted = align256(o_bsum + 1024 * 4);
  int* counts  = (int*)(ws + o_counts);
  int* row_ptr = (int*)(ws + o_rowptr);
  int* cursor  = (int*)(ws + o_cursor);
  int* bsum    = (int*)(ws + o_bsum);
  int* sorted  = (int*)(ws + o_sorted);

  const int nb = (n_dst + 1023) >> 10;  // scan blocks (<=1024 supported)

  hipMemsetAsync(counts, 0, (size_t)n_dst * 4, stream);
  hist_kernel<<<(n_edge + 255) / 256, 256, 0, stream>>>(dst_idx, counts, n_edge);
  scan1_kernel<<<nb, 1024, 0, stream>>>(counts, row_ptr, bsum, n_dst);
  scan2_kernel<<<1, 1024, 0, stream>>>(bsum, nb);
  scan3_kernel<<<(n_dst + 255) / 256, 256, 0, stream>>>(row_ptr, cursor, bsum, n_dst);
  fill_kernel<<<(n_edge + 255) / 256, 256, 0, stream>>>(src_idx, dst_idx, cursor,
                                                        sorted, n_edge);
  aggregate_kernel<<<(n_dst + 3) / 4, 256, 0, stream>>>(x, row_ptr, sorted, out, n_dst);

  const size_t lds_bytes = 65536 + 64 * 264 * 2;  // 99328
  hipFuncSetAttribute(reinterpret_cast<const void*>(finish_kernel),
                      hipFuncAttributeMaxDynamicSharedMemorySize, (int)lds_bytes);
  finish_kernel<<<(n_dst + 63) / 64, 256, lds_bytes, stream>>>(out, x, W1, W2, degree,
                                                               self_ids, n_dst);
}

// Round 3
// 184.814 us; speedup vs baseline: 2.8250x; 1.1387x over previous
//
#include <hip/hip_runtime.h>
#include <stdint.h>

#define DIM 128

typedef __attribute__((ext_vector_type(8))) short short8;
typedef __attribute__((ext_vector_type(4))) float f32x4;

static __device__ __forceinline__ uint16_t f2bf(float f) {
  uint32_t u = __builtin_bit_cast(uint32_t, f);
  uint32_t r = (u + 0x7fffu + ((u >> 16) & 1u)) >> 16;  // RNE
  return (uint16_t)r;
}
static __device__ __forceinline__ uint32_t pack2(float a, float b) {
  return (uint32_t)f2bf(a) | ((uint32_t)f2bf(b) << 16);
}

// ---------------- CSR build ----------------
__global__ __launch_bounds__(256) void hist_kernel(
    const int* __restrict__ dst, int* __restrict__ counts, int n_edge) {
  const int e = blockIdx.x * 256 + threadIdx.x;
  if (e < n_edge) atomicAdd(&counts[dst[e]], 1);
}

// Block-level inclusive scan; also (blocks 0..15) builds the frag-order bf16
// B table: b_tab[i] packs B[k][c],B[k+... ] per MFMA fragment layout so the
// GEMM can read B fragments directly from global (L1-resident, 32KB).
__global__ __launch_bounds__(1024) void scan1_kernel(
    const int* __restrict__ counts, int* __restrict__ row_ptr,
    int* __restrict__ bsum, int n,
    const float* __restrict__ W1, const float* __restrict__ W2,
    uint32_t* __restrict__ b_tab) {
  if (blockIdx.x < 16) {
    // frag(kst,ct): lane ln, elems j,j+1 -> B[k=kst*32+(ln>>4)*8+j][c=ct*16+(ln&15)]
    const int i = blockIdx.x * 1024 + threadIdx.x;  // 16384 u32 total
    const int e = i << 1;
    const int kst = e >> 12;
    const int ct  = (e >> 9) & 7;
    const int ln  = (e >> 3) & 63;
    const int j   = e & 7;
    const int k   = kst * 32 + ((ln >> 4) << 3) + j;
    const int c   = ct * 16 + (ln & 15);
    const float* w = (k < 128) ? (W1 + c * 128 + k) : (W2 + c * 128 + (k - 128));
    b_tab[i] = pack2(w[0], w[1]);
  }
  __shared__ int sm[1024];
  const int t = threadIdx.x, i = blockIdx.x * 1024 + t;
  int v = (i < n) ? counts[i] : 0;
  sm[t] = v;
  __syncthreads();
  for (int off = 1; off < 1024; off <<= 1) {
    int a = (t >= off) ? sm[t - off] : 0;
    __syncthreads();
    sm[t] += a;
    __syncthreads();
  }
  if (i < n) row_ptr[i + 1] = sm[t];
  if (t == 1023) bsum[blockIdx.x] = sm[t];
}

__global__ __launch_bounds__(1024) void scan2_kernel(int* __restrict__ bsum, int nb) {
  __shared__ int sm[1024];
  const int t = threadIdx.x;
  int v = (t < nb) ? bsum[t] : 0;
  sm[t] = v;
  __syncthreads();
  for (int off = 1; off < 1024; off <<= 1) {
    int a = (t >= off) ? sm[t - off] : 0;
    __syncthreads();
    sm[t] += a;
    __syncthreads();
  }
  if (t < nb) bsum[t] = sm[t] - v;  // exclusive
}

__global__ __launch_bounds__(256) void scan3_kernel(
    int* __restrict__ row_ptr, int* __restrict__ cursor,
    const int* __restrict__ bsum, int n) {
  const int i = blockIdx.x * 256 + threadIdx.x;
  if (i < n) {
    const int v = row_ptr[i + 1] + bsum[i >> 10];
    row_ptr[i + 1] = v;
    if (i + 1 < n) cursor[i + 1] = v;
    if (i == 0) { row_ptr[0] = 0; cursor[0] = 0; }
  }
}

__global__ __launch_bounds__(256) void fill_kernel(
    const int* __restrict__ src, const int* __restrict__ dst,
    int* __restrict__ cursor, int* __restrict__ sorted, int n_edge) {
  const int e = blockIdx.x * 256 + threadIdx.x;
  if (e < n_edge) {
    const int pos = atomicAdd(&cursor[dst[e]], 1);
    sorted[pos] = src[e];
  }
}

// ---------------- Fused aggregate + GEMM ----------------
// Block = 4 independent waves, each owns 16 dst rows. Per wave:
//   Phase A: pull-aggregate each row (CSR gather, f32 acc in regs), scale by
//            1/deg, pack bf16 -> own LDS tile; append x[self] row (K=128..255).
//   Phase B: 8x8 MFMA 16x16x32 from own LDS tile (A) x global b_tab (B).
// No __syncthreads anywhere — waves never share LDS.
// LDS tile: [16 rows][132 u32] (264 bf16; stride 528B keeps b128 reads
// 16B-aligned, rows land 2-way on banks = free per m136).
__global__ __launch_bounds__(256) void fused_kernel(
    const float* __restrict__ x, const int* __restrict__ row_ptr,
    const int* __restrict__ sorted, const float* __restrict__ degree,
    const int* __restrict__ self_ids, const uint32_t* __restrict__ b_tab,
    float* __restrict__ out, int n_dst)
{
  __shared__ uint32_t As[4][16][132];   // 33792 B -> 4 blocks/CU
  const int tid = threadIdx.x;
  const int w = tid >> 6, lane = tid & 63;
  const int rbase = blockIdx.x * 64 + w * 16;

  // Phase A
  for (int rr = 0; rr < 16; ++rr) {
    const int row = rbase + rr;
    if (row < n_dst) {
      const int beg = __builtin_amdgcn_readfirstlane(row_ptr[row]);
      const int end = __builtin_amdgcn_readfirstlane(row_ptr[row + 1]);
      float2 acc = {0.f, 0.f};
      for (int base = beg; base < end; base += 64) {
        const int m = end - base;
        const int myid = (lane < m) ? sorted[base + lane] : 0;
        const int cnt = m < 64 ? m : 64;
        for (int j = 0; j < cnt; ++j) {
          const int s = __shfl(myid, j);
          const float2 v = *reinterpret_cast<const float2*>(x + (size_t)s * DIM + lane * 2);
          acc.x += v.x;
          acc.y += v.y;
        }
      }
      const float inv = 1.0f / degree[row];
      As[w][rr][lane] = pack2(acc.x * inv, acc.y * inv);
      const int sid = __builtin_amdgcn_readfirstlane(self_ids[row]);
      const float2 v = *reinterpret_cast<const float2*>(x + (size_t)sid * DIM + lane * 2);
      As[w][rr][64 + lane] = pack2(v.x, v.y);
    } else {
      As[w][rr][lane] = 0;
      As[w][rr][64 + lane] = 0;
    }
  }

  // Phase B: A-frag: lane ln holds A[row=ln&15][k=kst*32+(ln>>4)*8 + j]
  const uint32_t* Arow = &As[w][lane & 15][(lane >> 4) << 2];
  const uint16_t* Bt = (const uint16_t*)b_tab;
  f32x4 acc[8] = {};
#pragma unroll
  for (int kst = 0; kst < 8; ++kst) {
    const short8 a = *reinterpret_cast<const short8*>(Arow + kst * 16);
#pragma unroll
    for (int ct = 0; ct < 8; ++ct) {
      const short8 b = *reinterpret_cast<const short8*>(Bt + (kst * 8 + ct) * 512 + lane * 8);
      acc[ct] = __builtin_amdgcn_mfma_f32_16x16x32_bf16(a, b, acc[ct], 0, 0, 0);
    }
  }

  // C/D (m89): col = lane&15, row = (lane>>4)*4 + reg.
  const int rout = rbase + ((lane >> 4) << 2);
  const int ccol = lane & 15;
#pragma unroll
  for (int ct = 0; ct < 8; ++ct) {
#pragma unroll
    for (int j = 0; j < 4; ++j) {
      const int row = rout + j;
      if (row < n_dst) out[(size_t)row * DIM + ct * 16 + ccol] = acc[ct][j];
    }
  }
}

extern "C" void kernel_launch(void* const* d_in, const int* in_sizes, int n_in,
                              void* d_out, int out_size, void* d_ws, size_t ws_size,
                              hipStream_t stream) {
  const float* x        = (const float*)d_in[0];
  const float* W1       = (const float*)d_in[1];
  const float* W2       = (const float*)d_in[2];
  const float* degree   = (const float*)d_in[3];
  const int*   src_idx  = (const int*)d_in[4];
  const int*   dst_idx  = (const int*)d_in[5];
  const int*   self_ids = (const int*)d_in[6];
  float* out = (float*)d_out;
  const int n_dst  = in_sizes[3];
  const int n_edge = in_sizes[4];

  // ws: counts | row_ptr | cursor | bsum | sorted | b_tab  (~3.3 MB)
  auto align256 = [](size_t v) { return (v + 255) & ~(size_t)255; };
  char* ws = (char*)d_ws;
  size_t o_counts = 0;
  size_t o_rowptr = align256(o_counts + (size_t)n_dst * 4);
  size_t o_cursor = align256(o_rowptr + (size_t)(n_dst + 1) * 4);
  size_t o_bsum   = align256(o_cursor + (size_t)n_dst * 4);
  size_t o_sorted = align256(o_bsum + 1024 * 4);
  size_t o_btab   = align256(o_sorted + (size_t)n_edge * 4);
  int* counts  = (int*)(ws + o_counts);
  int* row_ptr = (int*)(ws + o_rowptr);
  int* cursor  = (int*)(ws + o_cursor);
  int* bsum    = (int*)(ws + o_bsum);
  int* sorted  = (int*)(ws + o_sorted);
  uint32_t* b_tab = (uint32_t*)(ws + o_btab);

  const int nb = (n_dst + 1023) >> 10;

  hipMemsetAsync(counts, 0, (size_t)n_dst * 4, stream);
  hist_kernel<<<(n_edge + 255) / 256, 256, 0, stream>>>(dst_idx, counts, n_edge);
  scan1_kernel<<<nb, 1024, 0, stream>>>(counts, row_ptr, bsum, n_dst, W1, W2, b_tab);
  scan2_kernel<<<1, 1024, 0, stream>>>(bsum, nb);
  scan3_kernel<<<(n_dst + 255) / 256, 256, 0, stream>>>(row_ptr, cursor, bsum, n_dst);
  fill_kernel<<<(n_edge + 255) / 256, 256, 0, stream>>>(src_idx, dst_idx, cursor,
                                                        sorted, n_edge);
  fused_kernel<<<(n_dst + 63) / 64, 256, 0, stream>>>(x, row_ptr, sorted, degree,
                                                      self_ids, b_tab, out, n_dst);
}

// Round 4
// 142.888 us; speedup vs baseline: 3.6539x; 1.2934x over previous
//
#include <hip/hip_runtime.h>
#include <stdint.h>

#define DIM 128

typedef __attribute__((ext_vector_type(8))) short short8;
typedef __attribute__((ext_vector_type(4))) float f32x4;

static __device__ __forceinline__ uint16_t f2bf(float f) {
  uint32_t u = __builtin_bit_cast(uint32_t, f);
  uint32_t r = (u + 0x7fffu + ((u >> 16) & 1u)) >> 16;  // RNE
  return (uint16_t)r;
}
static __device__ __forceinline__ uint32_t pack2(float a, float b) {
  return (uint32_t)f2bf(a) | ((uint32_t)f2bf(b) << 16);
}
static __device__ __forceinline__ void add4(float4& a, const float4 b) {
  a.x += b.x; a.y += b.y; a.z += b.z; a.w += b.w;
}

// ---------------- CSR build ----------------
__global__ __launch_bounds__(256) void hist_kernel(
    const int* __restrict__ dst, int* __restrict__ counts, int n_edge) {
  const int e = blockIdx.x * 256 + threadIdx.x;
  if (e < n_edge) atomicAdd(&counts[dst[e]], 1);
}

// Block-level inclusive scan; blocks 0..15 also build the frag-order bf16 B
// table so the GEMM reads B fragments directly from global (64KB, L2-hot).
__global__ __launch_bounds__(1024) void scan1_kernel(
    const int* __restrict__ counts, int* __restrict__ row_ptr,
    int* __restrict__ bsum, int n,
    const float* __restrict__ W1, const float* __restrict__ W2,
    uint32_t* __restrict__ b_tab) {
  if (blockIdx.x < 16) {
    // frag(kst,ct): lane ln, elems j,j+1 -> B[k=kst*32+(ln>>4)*8+j][c=ct*16+(ln&15)]
    const int i = blockIdx.x * 1024 + threadIdx.x;  // 16384 u32 total
    const int e = i << 1;
    const int kst = e >> 12;
    const int ct  = (e >> 9) & 7;
    const int ln  = (e >> 3) & 63;
    const int j   = e & 7;
    const int k   = kst * 32 + ((ln >> 4) << 3) + j;
    const int c   = ct * 16 + (ln & 15);
    const float* w = (k < 128) ? (W1 + c * 128 + k) : (W2 + c * 128 + (k - 128));
    b_tab[i] = pack2(w[0], w[1]);
  }
  __shared__ int sm[1024];
  const int t = threadIdx.x, i = blockIdx.x * 1024 + t;
  int v = (i < n) ? counts[i] : 0;
  sm[t] = v;
  __syncthreads();
  for (int off = 1; off < 1024; off <<= 1) {
    int a = (t >= off) ? sm[t - off] : 0;
    __syncthreads();
    sm[t] += a;
    __syncthreads();
  }
  if (i < n) row_ptr[i + 1] = sm[t];
  if (t == 1023) bsum[blockIdx.x] = sm[t];
}

__global__ __launch_bounds__(1024) void scan2_kernel(int* __restrict__ bsum, int nb) {
  __shared__ int sm[1024];
  const int t = threadIdx.x;
  int v = (t < nb) ? bsum[t] : 0;
  sm[t] = v;
  __syncthreads();
  for (int off = 1; off < 1024; off <<= 1) {
    int a = (t >= off) ? sm[t - off] : 0;
    __syncthreads();
    sm[t] += a;
    __syncthreads();
  }
  if (t < nb) bsum[t] = sm[t] - v;  // exclusive
}

__global__ __launch_bounds__(256) void scan3_kernel(
    int* __restrict__ row_ptr, int* __restrict__ cursor,
    const int* __restrict__ bsum, int n) {
  const int i = blockIdx.x * 256 + threadIdx.x;
  if (i < n) {
    const int v = row_ptr[i + 1] + bsum[i >> 10];
    row_ptr[i + 1] = v;
    if (i + 1 < n) cursor[i + 1] = v;
    if (i == 0) { row_ptr[0] = 0; cursor[0] = 0; }
  }
}

__global__ __launch_bounds__(256) void fill_kernel(
    const int* __restrict__ src, const int* __restrict__ dst,
    int* __restrict__ cursor, int* __restrict__ sorted, int n_edge) {
  const int e = blockIdx.x * 256 + threadIdx.x;
  if (e < n_edge) {
    const int pos = atomicAdd(&cursor[dst[e]], 1);
    sorted[pos] = src[e];
  }
}

// ---------------- Fused aggregate + GEMM ----------------
// Block = 4 independent waves, each owns 16 dst rows (no __syncthreads).
// Phase A (latency-optimized): wave splits into 4 groups of 16 lanes; group g
// aggregates row rit*4+g (8 floats/lane via 2x float4). All per-row metadata
// (row_ptr, self_ids, degree) prefetched once and shfl-broadcast; edge loop is
// 2-stage software-pipelined so x-row gathers stay in flight.
// Phase B: 8x8 MFMA 16x16x32 from own LDS tile (A) x global b_tab (B).
__global__ __launch_bounds__(256) void fused_kernel(
    const float* __restrict__ x, const int* __restrict__ row_ptr,
    const int* __restrict__ sorted, const float* __restrict__ degree,
    const int* __restrict__ self_ids, const uint32_t* __restrict__ b_tab,
    float* __restrict__ out, int n_dst)
{
  __shared__ uint32_t As[4][16][132];   // 33792 B; per-wave tiles, stride 528B
  const int tid = threadIdx.x;
  const int w = tid >> 6, lane = tid & 63;
  const int g = lane >> 4, li = lane & 15;
  const int rbase = blockIdx.x * 64 + w * 16;

  // Prefetch per-row metadata for the wave's 16 rows.
  int rp = 0, sid_all = 0;
  float deg_all = 1.f;
  if (lane < 17) {
    const int idx = rbase + lane;
    rp = row_ptr[idx > n_dst ? n_dst : idx];
  }
  if (lane < 16) {
    const int r = rbase + lane;
    const int rc = (r < n_dst) ? r : 0;
    sid_all = self_ids[rc];
    deg_all = degree[rc];
  }

  // Phase A: 4 rounds; group g handles row rbase + rit*4 + g.
  for (int rit = 0; rit < 4; ++rit) {
    const int rr = rit * 4 + g;
    const int beg = __shfl(rp, rr);
    const int end = __shfl(rp, rr + 1);
    const int sid = __shfl(sid_all, rr);
    const float inv = 1.0f / __shfl(deg_all, rr);

    // Self row: issue early, consumed at the end.
    const float4* xs = reinterpret_cast<const float4*>(x + (size_t)sid * DIM + li * 8);
    const float4 s0 = xs[0], s1 = xs[1];

    float4 a0 = {0.f, 0.f, 0.f, 0.f}, a1 = {0.f, 0.f, 0.f, 0.f};
    for (int base = beg; base < end; base += 16) {
      const int m = end - base;
      const int cnt = m < 16 ? m : 16;
      const int myid = (li < m) ? sorted[base + li] : 0;
      // 2-stage pipeline: load edge j+1 while accumulating edge j.
      int s = __shfl(myid, g * 16);
      const float4* p = reinterpret_cast<const float4*>(x + (size_t)s * DIM + li * 8);
      float4 v0 = p[0], v1 = p[1];
      for (int j = 1; j < cnt; ++j) {
        const int sn = __shfl(myid, g * 16 + j);
        const float4* pn = reinterpret_cast<const float4*>(x + (size_t)sn * DIM + li * 8);
        const float4 n0 = pn[0], n1 = pn[1];
        add4(a0, v0); add4(a1, v1);
        v0 = n0; v1 = n1;
      }
      add4(a0, v0); add4(a1, v1);
    }

    uint4 pa;
    pa.x = pack2(a0.x * inv, a0.y * inv);
    pa.y = pack2(a0.z * inv, a0.w * inv);
    pa.z = pack2(a1.x * inv, a1.y * inv);
    pa.w = pack2(a1.z * inv, a1.w * inv);
    *reinterpret_cast<uint4*>(&As[w][rr][li * 4]) = pa;
    uint4 ps;
    ps.x = pack2(s0.x, s0.y);
    ps.y = pack2(s0.z, s0.w);
    ps.z = pack2(s1.x, s1.y);
    ps.w = pack2(s1.z, s1.w);
    *reinterpret_cast<uint4*>(&As[w][rr][64 + li * 4]) = ps;
  }

  // Phase B: A-frag lane ln holds A[row=ln&15][k=kst*32+(ln>>4)*8+j], j=0..7.
  const uint32_t* Arow = &As[w][lane & 15][(lane >> 4) << 2];
  const uint16_t* Bt = (const uint16_t*)b_tab;
  f32x4 acc[8] = {};
#pragma unroll
  for (int kst = 0; kst < 8; ++kst) {
    const short8 a = *reinterpret_cast<const short8*>(Arow + kst * 16);
#pragma unroll
    for (int ct = 0; ct < 8; ++ct) {
      const short8 b = *reinterpret_cast<const short8*>(Bt + (kst * 8 + ct) * 512 + lane * 8);
      acc[ct] = __builtin_amdgcn_mfma_f32_16x16x32_bf16(a, b, acc[ct], 0, 0, 0);
    }
  }

  // C/D (m89): col = lane&15, row = (lane>>4)*4 + reg.
  const int rout = rbase + ((lane >> 4) << 2);
  const int ccol = lane & 15;
#pragma unroll
  for (int ct = 0; ct < 8; ++ct) {
#pragma unroll
    for (int j = 0; j < 4; ++j) {
      const int row = rout + j;
      if (row < n_dst) out[(size_t)row * DIM + ct * 16 + ccol] = acc[ct][j];
    }
  }
}

extern "C" void kernel_launch(void* const* d_in, const int* in_sizes, int n_in,
                              void* d_out, int out_size, void* d_ws, size_t ws_size,
                              hipStream_t stream) {
  const float* x        = (const float*)d_in[0];
  const float* W1       = (const float*)d_in[1];
  const float* W2       = (const float*)d_in[2];
  const float* degree   = (const float*)d_in[3];
  const int*   src_idx  = (const int*)d_in[4];
  const int*   dst_idx  = (const int*)d_in[5];
  const int*   self_ids = (const int*)d_in[6];
  float* out = (float*)d_out;
  const int n_dst  = in_sizes[3];
  const int n_edge = in_sizes[4];

  // ws: counts | row_ptr | cursor | bsum | sorted | b_tab  (~3.3 MB)
  auto align256 = [](size_t v) { return (v + 255) & ~(size_t)255; };
  char* ws = (char*)d_ws;
  size_t o_counts = 0;
  size_t o_rowptr = align256(o_counts + (size_t)n_dst * 4);
  size_t o_cursor = align256(o_rowptr + (size_t)(n_dst + 1) * 4);
  size_t o_bsum   = align256(o_cursor + (size_t)n_dst * 4);
  size_t o_sorted = align256(o_bsum + 1024 * 4);
  size_t o_btab   = align256(o_sorted + (size_t)n_edge * 4);
  int* counts  = (int*)(ws + o_counts);
  int* row_ptr = (int*)(ws + o_rowptr);
  int* cursor  = (int*)(ws + o_cursor);
  int* bsum    = (int*)(ws + o_bsum);
  int* sorted  = (int*)(ws + o_sorted);
  uint32_t* b_tab = (uint32_t*)(ws + o_btab);

  const int nb = (n_dst + 1023) >> 10;

  hipMemsetAsync(counts, 0, (size_t)n_dst * 4, stream);
  hist_kernel<<<(n_edge + 255) / 256, 256, 0, stream>>>(dst_idx, counts, n_edge);
  scan1_kernel<<<nb, 1024, 0, stream>>>(counts, row_ptr, bsum, n_dst, W1, W2, b_tab);
  scan2_kernel<<<1, 1024, 0, stream>>>(bsum, nb);
  scan3_kernel<<<(n_dst + 255) / 256, 256, 0, stream>>>(row_ptr, cursor, bsum, n_dst);
  fill_kernel<<<(n_edge + 255) / 256, 256, 0, stream>>>(src_idx, dst_idx, cursor,
                                                        sorted, n_edge);
  fused_kernel<<<(n_dst + 63) / 64, 256, 0, stream>>>(x, row_ptr, sorted, degree,
                                                      self_ids, b_tab, out, n_dst);
}

// Round 5
// 126.222 us; speedup vs baseline: 4.1364x; 1.1320x over previous
//
#include <hip/hip_runtime.h>
#include <stdint.h>

#define DIM 128

typedef __attribute__((ext_vector_type(8))) short short8;
typedef __attribute__((ext_vector_type(4))) float f32x4;

static __device__ __forceinline__ uint16_t f2bf(float f) {
  uint32_t u = __builtin_bit_cast(uint32_t, f);
  uint32_t r = (u + 0x7fffu + ((u >> 16) & 1u)) >> 16;  // RNE
  return (uint16_t)r;
}
static __device__ __forceinline__ uint32_t pack2(float a, float b) {
  return (uint32_t)f2bf(a) | ((uint32_t)f2bf(b) << 16);
}
static __device__ __forceinline__ void add4(float4& a, const float4 b) {
  a.x += b.x; a.y += b.y; a.z += b.z; a.w += b.w;
}

// ---------------- CSR build ----------------
// hist: edge histogram; blocks 0..63 also build the frag-order bf16 B table
// (b_tab, 64KB) so the GEMM reads B fragments directly from global (L2-hot).
__global__ __launch_bounds__(256) void hist_kernel(
    const int* __restrict__ dst, int* __restrict__ counts, int n_edge,
    const float* __restrict__ W1, const float* __restrict__ W2,
    uint32_t* __restrict__ b_tab) {
  const int gid = blockIdx.x * 256 + threadIdx.x;
  if (gid < 16384) {
    // frag(kst,ct): lane ln, elems j,j+1 -> B[k=kst*32+(ln>>4)*8+j][c=ct*16+(ln&15)]
    const int e = gid << 1;
    const int kst = e >> 12;
    const int ct  = (e >> 9) & 7;
    const int ln  = (e >> 3) & 63;
    const int j   = e & 7;
    const int k   = kst * 32 + ((ln >> 4) << 3) + j;
    const int c   = ct * 16 + (ln & 15);
    const float* wp = (k < 128) ? (W1 + c * 128 + k) : (W2 + c * 128 + (k - 128));
    b_tab[gid] = pack2(wp[0], wp[1]);
  }
  if (gid < n_edge) atomicAdd(&counts[dst[gid]], 1);
}

// Block-level inclusive scan (1024/block); row_ptr[i+1] = partial, bsum[b] = total.
__global__ __launch_bounds__(1024) void scan1_kernel(
    const int* __restrict__ counts, int* __restrict__ row_ptr,
    int* __restrict__ bsum, int n) {
  __shared__ int sm[1024];
  const int t = threadIdx.x, i = blockIdx.x * 1024 + t;
  int v = (i < n) ? counts[i] : 0;
  sm[t] = v;
  __syncthreads();
  for (int off = 1; off < 1024; off <<= 1) {
    int a = (t >= off) ? sm[t - off] : 0;
    __syncthreads();
    sm[t] += a;
    __syncthreads();
  }
  if (i < n) row_ptr[i + 1] = sm[t];
  if (t == 1023) bsum[blockIdx.x] = sm[t];
}

// Apply block offsets (each 256-block spans exactly one scan1 block since
// 256 | 1024 -> one prefix value per block, computed inline by wave 0).
__global__ __launch_bounds__(256) void scan3_kernel(
    int* __restrict__ row_ptr, int* __restrict__ cursor,
    const int* __restrict__ bsum, int n) {
  __shared__ int soff;
  const int t = threadIdx.x;
  const int nbp = (int)(blockIdx.x >> 2);  // # scan1 blocks before mine
  if (t < 64) {
    int acc = 0;
    for (int b = t; b < nbp; b += 64) acc += bsum[b];
    for (int off = 32; off; off >>= 1) acc += __shfl_down(acc, off);
    if (t == 0) soff = acc;
  }
  __syncthreads();
  const int off = soff;
  const int i = blockIdx.x * 256 + t;
  if (i < n) {
    const int v = row_ptr[i + 1] + off;
    row_ptr[i + 1] = v;
    if (i + 1 < n) cursor[i + 1] = v;
    if (i == 0) { row_ptr[0] = 0; cursor[0] = 0; }
  }
}

__global__ __launch_bounds__(256) void fill_kernel(
    const int* __restrict__ src, const int* __restrict__ dst,
    int* __restrict__ cursor, int* __restrict__ sorted, int n_edge) {
  const int e = blockIdx.x * 256 + threadIdx.x;
  if (e < n_edge) {
    const int pos = atomicAdd(&cursor[dst[e]], 1);
    sorted[pos] = src[e];
  }
}

// ---------------- Fused aggregate + GEMM ----------------
// Block = 4 independent waves, each owns 16 dst rows; wave splits into 4
// groups of 16 lanes; group g owns rows g*4..g*4+3 (8 floats/lane).
// Latency plan: ALL independent loads (4 id-chunks, 4 self rows, metadata)
// issue before any accumulation; edge gathers run in depth-4 batches
// (8 float4 in flight per lane). LDS caps occupancy at 16 waves/CU, so
// __launch_bounds__(256,4) allows the full 128-VGPR budget.
__global__ __launch_bounds__(256, 4) void fused_kernel(
    const float* __restrict__ x, const int* __restrict__ row_ptr,
    const int* __restrict__ sorted, const float* __restrict__ degree,
    const int* __restrict__ self_ids, const uint32_t* __restrict__ b_tab,
    float* __restrict__ out, int n_dst)
{
  __shared__ uint32_t As[4][16][132];   // per-wave tiles, stride 528B
  const int tid = threadIdx.x;
  const int w = tid >> 6, lane = tid & 63;
  const int g = lane >> 4, li = lane & 15;
  const int rbase = blockIdx.x * 64 + w * 16;

  // Wave-wide metadata prefetch.
  int rp = 0, sid_all = 0;
  float deg_all = 1.f;
  if (lane < 17) {
    const int idx = rbase + lane;
    rp = row_ptr[idx > n_dst ? n_dst : idx];
  }
  if (lane < 16) {
    const int r = rbase + lane;
    const int rc = (r < n_dst) ? r : 0;
    sid_all = self_ids[rc];
    deg_all = degree[rc];
  }

  int beg[4], end[4], sid[4];
  float inv[4];
#pragma unroll
  for (int r = 0; r < 4; ++r) {
    const int rr = g * 4 + r;
    beg[r] = __shfl(rp, rr);
    end[r] = __shfl(rp, rr + 1);
    sid[r] = __shfl(sid_all, rr);
    inv[r] = 1.0f / __shfl(deg_all, rr);
  }
  // Prefetch first id-chunk of each row (4 independent loads).
  int ids[4];
#pragma unroll
  for (int r = 0; r < 4; ++r)
    ids[r] = (li < end[r] - beg[r]) ? sorted[beg[r] + li] : 0;
  // Prefetch self rows (8 independent float4 loads).
  float4 s0[4], s1[4];
#pragma unroll
  for (int r = 0; r < 4; ++r) {
    const float4* xs = reinterpret_cast<const float4*>(x + (size_t)sid[r] * DIM + li * 8);
    s0[r] = xs[0];
    s1[r] = xs[1];
  }

#pragma unroll
  for (int r = 0; r < 4; ++r) {
    const int rr = g * 4 + r;
    float4 a0 = {0.f, 0.f, 0.f, 0.f}, a1 = {0.f, 0.f, 0.f, 0.f};
    int base = beg[r];
    int chunk = ids[r];
    for (;;) {
      const int m = end[r] - base;
      const int cnt = m < 16 ? m : 16;
      for (int jb = 0; jb < cnt; jb += 4) {
        float4 v0[4], v1[4];
#pragma unroll
        for (int u = 0; u < 4; ++u) {
          const int s = __shfl(chunk, g * 16 + ((jb + u) & 15));
          const float4* p = reinterpret_cast<const float4*>(x + (size_t)s * DIM + li * 8);
          v0[u] = p[0];
          v1[u] = p[1];
        }
#pragma unroll
        for (int u = 0; u < 4; ++u) {
          if (jb + u < cnt) { add4(a0, v0[u]); add4(a1, v1[u]); }
        }
      }
      base += 16;
      if (base >= end[r]) break;
      chunk = (li < end[r] - base) ? sorted[base + li] : 0;  // rare (deg>16)
    }

    uint4 pa;
    pa.x = pack2(a0.x * inv[r], a0.y * inv[r]);
    pa.y = pack2(a0.z * inv[r], a0.w * inv[r]);
    pa.z = pack2(a1.x * inv[r], a1.y * inv[r]);
    pa.w = pack2(a1.z * inv[r], a1.w * inv[r]);
    *reinterpret_cast<uint4*>(&As[w][rr][li * 4]) = pa;
    uint4 ps;
    ps.x = pack2(s0[r].x, s0[r].y);
    ps.y = pack2(s0[r].z, s0[r].w);
    ps.z = pack2(s1[r].x, s1[r].y);
    ps.w = pack2(s1[r].z, s1[r].w);
    *reinterpret_cast<uint4*>(&As[w][rr][64 + li * 4]) = ps;
  }

  // Phase B: A-frag lane ln holds A[row=ln&15][k=kst*32+(ln>>4)*8+j], j=0..7.
  // (wave-synchronous: same wave wrote the whole tile; no barrier needed)
  const uint32_t* Arow = &As[w][lane & 15][(lane >> 4) << 2];
  const uint16_t* Bt = (const uint16_t*)b_tab;
  f32x4 acc[8] = {};
#pragma unroll
  for (int kst = 0; kst < 8; ++kst) {
    const short8 a = *reinterpret_cast<const short8*>(Arow + kst * 16);
#pragma unroll
    for (int ct = 0; ct < 8; ++ct) {
      const short8 b = *reinterpret_cast<const short8*>(Bt + (kst * 8 + ct) * 512 + lane * 8);
      acc[ct] = __builtin_amdgcn_mfma_f32_16x16x32_bf16(a, b, acc[ct], 0, 0, 0);
    }
  }

  // C/D (m89): col = lane&15, row = (lane>>4)*4 + reg.
  const int rout = rbase + ((lane >> 4) << 2);
  const int ccol = lane & 15;
#pragma unroll
  for (int ct = 0; ct < 8; ++ct) {
#pragma unroll
    for (int j = 0; j < 4; ++j) {
      const int row = rout + j;
      if (row < n_dst) out[(size_t)row * DIM + ct * 16 + ccol] = acc[ct][j];
    }
  }
}

extern "C" void kernel_launch(void* const* d_in, const int* in_sizes, int n_in,
                              void* d_out, int out_size, void* d_ws, size_t ws_size,
                              hipStream_t stream) {
  const float* x        = (const float*)d_in[0];
  const float* W1       = (const float*)d_in[1];
  const float* W2       = (const float*)d_in[2];
  const float* degree   = (const float*)d_in[3];
  const int*   src_idx  = (const int*)d_in[4];
  const int*   dst_idx  = (const int*)d_in[5];
  const int*   self_ids = (const int*)d_in[6];
  float* out = (float*)d_out;
  const int n_dst  = in_sizes[3];
  const int n_edge = in_sizes[4];

  // ws: counts | row_ptr | cursor | bsum | sorted | b_tab  (~3.3 MB)
  auto align256 = [](size_t v) { return (v + 255) & ~(size_t)255; };
  char* ws = (char*)d_ws;
  size_t o_counts = 0;
  size_t o_rowptr = align256(o_counts + (size_t)n_dst * 4);
  size_t o_cursor = align256(o_rowptr + (size_t)(n_dst + 1) * 4);
  size_t o_bsum   = align256(o_cursor + (size_t)n_dst * 4);
  size_t o_sorted = align256(o_bsum + 1024 * 4);
  size_t o_btab   = align256(o_sorted + (size_t)n_edge * 4);
  int* counts  = (int*)(ws + o_counts);
  int* row_ptr = (int*)(ws + o_rowptr);
  int* cursor  = (int*)(ws + o_cursor);
  int* bsum    = (int*)(ws + o_bsum);
  int* sorted  = (int*)(ws + o_sorted);
  uint32_t* b_tab = (uint32_t*)(ws + o_btab);

  const int nb = (n_dst + 1023) >> 10;

  hipMemsetAsync(counts, 0, (size_t)n_dst * 4, stream);
  hist_kernel<<<(n_edge + 255) / 256, 256, 0, stream>>>(dst_idx, counts, n_edge,
                                                        W1, W2, b_tab);
  scan1_kernel<<<nb, 1024, 0, stream>>>(counts, row_ptr, bsum, n_dst);
  scan3_kernel<<<(n_dst + 255) / 256, 256, 0, stream>>>(row_ptr, cursor, bsum, n_dst);
  fill_kernel<<<(n_edge + 255) / 256, 256, 0, stream>>>(src_idx, dst_idx, cursor,
                                                        sorted, n_edge);
  fused_kernel<<<(n_dst + 63) / 64, 256, 0, stream>>>(x, row_ptr, sorted, degree,
                                                      self_ids, b_tab, out, n_dst);
}